// Round 19
// baseline (103.138 us; speedup 1.0000x reference)
//
#include <hip/hip_runtime.h>
#include <hip/hip_bf16.h>

typedef __bf16 bf16x8 __attribute__((ext_vector_type(8)));
typedef float  f32x4  __attribute__((ext_vector_type(4)));
typedef float  f32x16 __attribute__((ext_vector_type(16)));

// async 16B global -> LDS (wave-uniform LDS base + lane*16; global addr per-lane)
__device__ __forceinline__ void gload_lds16(const void* g, void* l) {
  __builtin_amdgcn_global_load_lds(
      (const __attribute__((address_space(1))) unsigned int*)g,
      (__attribute__((address_space(3))) unsigned int*)l, 16, 0, 0);
}

// XCD-aware bijective remap for a (16, 32) grid (attn): blocks sharing y -> one XCD.
__device__ __forceinline__ void xcd_remap(int& x, int& y) {
  const int lin = blockIdx.x + (blockIdx.y << 4);   // 0..511
  const int xcd = lin & 7, slot = lin >> 3;         // slot 0..63
  y = ((slot >> 4) << 3) + xcd;                     // 0..31
  x = slot & 15;                                    // 0..15
}

// ---------------- fused fp32 -> bf16 convert: x, Wq, Wo in one launch ----------------
__global__ void k_cvt3(const float* __restrict__ x, const float* __restrict__ wq,
                       const float* __restrict__ wo, __bf16* __restrict__ xb,
                       __bf16* __restrict__ wqb, __bf16* __restrict__ wob) {
  const int i = blockIdx.x * 256 + threadIdx.x;     // 0..1572863 (x 1M, wq 256K, wo 256K f4)
  const float* s; __bf16* d; int j;
  if (i < 1048576)      { s = x;  d = xb;  j = i; }
  else if (i < 1310720) { s = wq; d = wqb; j = i - 1048576; }
  else                  { s = wo; d = wob; j = i - 1310720; }
  float4 v = ((const float4*)s)[j];
  union { __bf16 h[4]; uint2 u; } o;
  o.h[0] = (__bf16)v.x; o.h[1] = (__bf16)v.y;
  o.h[2] = (__bf16)v.z; o.h[3] = (__bf16)v.w;
  ((uint2*)d)[j] = o.u;
}

// ---------------- C[M,N] = A[M,K] @ B[N,K]^T + bias ----------------
// NEW: 128x128 tile, 4 waves 2x2 (wave-tile 64x64), 32x32x16 MFMA (2x FLOP per
// operand byte -> 1.5x less LDS read traffic per FLOP; GEMM was LDS-BW-bound).
// grid (8,32) = 256 blocks = 1 blk/CU; launch_bounds(256,1) -> 512-VGPR cap
// (acc = 4x f32x16 = 64 regs). 4 LDS buffers, depth-2 prefetch, counted vmcnt(8),
// one raw barrier/iter (race-audit: buffer reused at distance 4; a wave stages
// buf[it+2] only after barrier(it-1), by which time all waves' reads of that
// buffer (iter it-2) completed -- lgkm waits precede the MFMAs that precede the
// barrier in program order).
// LDS swizzle (row stride 64B would be 2-bank): elem = row*32 + (col ^ ((row&3)<<3)).
// b128 frag reads then hit each bank exactly 4x (the 1KB/wave minimum).
// Staged via pre-swizzled per-lane GLOBAL addresses, linear LDS dest (m173):
// DMA lane l of wave w, call c covers LDS elems c*2048 + w*512 + 8l =>
// row = c*64 + w*16 + (l>>2), stored col-group 8(l&3) = source col-group
// 8((l&3) ^ (row&3)), row&3 = (l>>2)&3.
template<bool OUT_BF16>
__global__ __launch_bounds__(256, 1)
void k_gemm_bt(const __bf16* __restrict__ A, const __bf16* __restrict__ B,
               const float* __restrict__ bias, void* __restrict__ C,
               int M, int N, int K) {
  __shared__ __align__(16) __bf16 At[4][128 * 32];   // 32KB
  __shared__ __align__(16) __bf16 Bt[4][128 * 32];   // 32KB
  const int tid  = threadIdx.x;
  const int lane = tid & 63;
  const int w    = tid >> 6;
  const int wr   = w >> 1, wc = w & 1;
  const int l31  = lane & 31, h = lane >> 5;
  // (8,32)-grid XCD remap: 4 y-panels per XCD -> A-panel fetched once per XCD
  const int lin = blockIdx.x + (blockIdx.y << 3);    // 0..255
  const int xcd = lin & 7, slot = lin >> 3;          // 0..31
  const int bm = (xcd * 4 + (slot >> 3)) * 128;
  const int bn = (slot & 7) * 128;

  f32x16 acc[2][2] = {};   // acc[af][bf]: rows wr*64+af*32+rowmap, cols wc*64+bf*32+l31

  // staging source addresses (pre-swizzled col group)
  const int kg = (((lane & 3) ^ ((lane >> 2) & 3)) << 3);
  const __bf16* ga = A + (size_t)(bm + w * 16 + (lane >> 2)) * K + kg;
  const __bf16* gb = B + (size_t)(bn + w * 16 + (lane >> 2)) * K + kg;

#define STAGE(buf, k0)                                                  \
  gload_lds16(ga + (k0),                  &At[buf][w * 512]);           \
  gload_lds16(ga + (k0) + (size_t)64 * K, &At[buf][2048 + w * 512]);    \
  gload_lds16(gb + (k0),                  &Bt[buf][w * 512]);           \
  gload_lds16(gb + (k0) + (size_t)64 * K, &Bt[buf][2048 + w * 512]);

  STAGE(0, 0)
  STAGE(1, 32)

  const int NIT = K / 32;                      // 32
  for (int it = 0; it < NIT; ++it) {
    const int cur = it & 3;
    if (it + 2 < NIT) {
      STAGE((it + 2) & 3, (it + 2) * 32)
      asm volatile("s_waitcnt vmcnt(8)" ::: "memory");   // retire tile it (it+1,it+2 in flight)
    } else if (it + 2 == NIT) {
      asm volatile("s_waitcnt vmcnt(4)" ::: "memory");
    } else {
      asm volatile("s_waitcnt vmcnt(0)" ::: "memory");
    }
    __builtin_amdgcn_s_barrier();
    __builtin_amdgcn_sched_barrier(0);

    bf16x8 a[2][2], b[2][2];   // [af|bf][ks]
#pragma unroll
    for (int af = 0; af < 2; ++af)
#pragma unroll
      for (int ks = 0; ks < 2; ++ks) {
        const int row = wr * 64 + af * 32 + l31;
        const int col = (ks * 16 + h * 8) ^ ((l31 & 3) << 3);
        a[af][ks] = *(const bf16x8*)&At[cur][row * 32 + col];
      }
#pragma unroll
    for (int bf = 0; bf < 2; ++bf)
#pragma unroll
      for (int ks = 0; ks < 2; ++ks) {
        const int row = wc * 64 + bf * 32 + l31;
        const int col = (ks * 16 + h * 8) ^ ((l31 & 3) << 3);
        b[bf][ks] = *(const bf16x8*)&Bt[cur][row * 32 + col];
      }
    __builtin_amdgcn_s_setprio(1);
#pragma unroll
    for (int ks = 0; ks < 2; ++ks)
#pragma unroll
      for (int af = 0; af < 2; ++af)
#pragma unroll
        for (int bf = 0; bf < 2; ++bf)
          acc[af][bf] = __builtin_amdgcn_mfma_f32_32x32x16_bf16(a[af][ks], b[bf][ks], acc[af][bf], 0, 0, 0);
    __builtin_amdgcn_s_setprio(0);
  }
#undef STAGE

  // epilogue: C row = bm + wr*64 + af*32 + (r&3)+8*(r>>2)+4h ; col = bn + wc*64 + bf*32 + l31
#pragma unroll
  for (int bf = 0; bf < 2; ++bf) {
    const int col = bn + wc * 64 + bf * 32 + l31;
    const float bv = bias[col];
#pragma unroll
    for (int af = 0; af < 2; ++af) {
#pragma unroll
      for (int r = 0; r < 16; ++r) {
        const int row = bm + wr * 64 + af * 32 + (r & 3) + 8 * (r >> 2) + 4 * h;
        const float v = acc[af][bf][r] + bv;
        if (OUT_BF16) ((__bf16*)C)[(size_t)row * N + col] = (__bf16)v;
        else          ((float*)C)[(size_t)row * N + col]  = v;
      }
    }
  }
}

// ---------------- flash attention (Q = K = V), 32x32x16 MFMA ---------------- (r18 proven, verbatim)
#define SWZ2(row, col) ((row) * 64 + ((col) ^ (((((row) & 7) ^ ((row) >> 3)) & 7) << 3)))

#define ATTN_TILE(T, KB, VB)                                                  \
  {                                                                           \
    *(bf16x8*)&KB[SWZ2(2 * sm, c0)]     = v0;                                 \
    *(bf16x8*)&KB[SWZ2(2 * sm + 1, c0)] = v1;                                 \
    _Pragma("unroll")                                                         \
    for (int j = 0; j < 8; ++j) {                                             \
      union { __bf16 b[2]; unsigned u; } pk;                                  \
      pk.b[0] = v0[j]; pk.b[1] = v1[j];                                       \
      *(unsigned*)&VB[SWZ2(c0 + j, 2 * sm)] = pk.u;                           \
    }                                                                         \
    __syncthreads();                                                          \
    if ((T) < 31) {                                                           \
      v0 = *(const bf16x8*)&gsrc[(size_t)((T) + 1) * 64 * 1024];              \
      v1 = *(const bf16x8*)&gsrc[(size_t)((T) + 1) * 64 * 1024 + 1024];       \
    }                                                                         \
    f32x16 s[2] = {};                                                         \
    _Pragma("unroll")                                                         \
    for (int kvf = 0; kvf < 2; ++kvf) {                                       \
      __builtin_amdgcn_s_setprio(1);                                          \
      _Pragma("unroll")                                                       \
      for (int ks = 0; ks < 4; ++ks) {                                        \
        bf16x8 ka = *(const bf16x8*)&KB[SWZ2(kvf * 32 + l31, ks * 16 + h * 8)]; \
        s[kvf] = __builtin_amdgcn_mfma_f32_32x32x16_bf16(ka, qb[ks], s[kvf], 0, 0, 0); \
      }                                                                       \
      __builtin_amdgcn_s_setprio(0);                                          \
    }                                                                         \
    unsigned P[2][4][2];                                                      \
    _Pragma("unroll")                                                         \
    for (int kvf = 0; kvf < 2; ++kvf) {                                       \
      _Pragma("unroll")                                                       \
      for (int rq = 0; rq < 4; ++rq) {                                        \
        _Pragma("unroll")                                                     \
        for (int tt = 0; tt < 2; ++tt) {                                      \
          const float p0 = __builtin_amdgcn_exp2f(s[kvf][rq * 4 + tt * 2]);   \
          const float p1 = __builtin_amdgcn_exp2f(s[kvf][rq * 4 + tt * 2 + 1]); \
          union { __bf16 b[2]; unsigned u; } pk;                              \
          pk.b[0] = (__bf16)p0; pk.b[1] = (__bf16)p1;                         \
          P[kvf][rq][tt] = pk.u;                                              \
        }                                                                     \
      }                                                                       \
    }                                                                         \
    _Pragma("unroll")                                                         \
    for (int ko = 0; ko < 4; ++ko) {                                          \
      const int kvf = ko >> 1, rqa = (ko & 1) * 2, rqb = rqa + 1;             \
      asm volatile("v_permlane32_swap_b32 %0, %1"                             \
                   : "+v"(P[kvf][rqa][0]), "+v"(P[kvf][rqb][0]));             \
      asm volatile("v_permlane32_swap_b32 %0, %1"                             \
                   : "+v"(P[kvf][rqa][1]), "+v"(P[kvf][rqb][1]));             \
    }                                                                         \
    __builtin_amdgcn_s_setprio(1);                                            \
    _Pragma("unroll")                                                         \
    for (int ko = 0; ko < 4; ++ko) {                                          \
      const int kvf = ko >> 1, rqa = (ko & 1) * 2, rqb = rqa + 1;             \
      union { unsigned u[4]; bf16x8 v; } pu;                                  \
      pu.u[0] = P[kvf][rqa][0]; pu.u[1] = P[kvf][rqa][1];                     \
      pu.u[2] = P[kvf][rqb][0]; pu.u[3] = P[kvf][rqb][1];                     \
      Osum = __builtin_amdgcn_mfma_f32_32x32x16_bf16(pu.v, onesb, Osum, 0, 0, 0); \
      bf16x8 vb0 = *(const bf16x8*)&VB[SWZ2(l31,      ko * 16 + h * 8)];      \
      bf16x8 vb1 = *(const bf16x8*)&VB[SWZ2(32 + l31, ko * 16 + h * 8)];      \
      O[0] = __builtin_amdgcn_mfma_f32_32x32x16_bf16(pu.v, vb0, O[0], 0, 0, 0); \
      O[1] = __builtin_amdgcn_mfma_f32_32x32x16_bf16(pu.v, vb1, O[1], 0, 0, 0); \
    }                                                                         \
    __builtin_amdgcn_s_setprio(0);                                            \
  }

__global__ __launch_bounds__(256, 2)
void k_attn(const __bf16* __restrict__ q, __bf16* __restrict__ o) {
  __shared__ __align__(16) __bf16 Kt[2][64 * 64];
  __shared__ __align__(16) __bf16 Vt[2][64 * 64];
  const int tid = threadIdx.x, lane = tid & 63;
  const int w = tid >> 6;
  const int l31 = lane & 31, h = lane >> 5;
  int bqx, bh; xcd_remap(bqx, bh);
  const size_t base = ((size_t)(bh >> 4) * 2048) * 1024 + (bh & 15) * 64;
  const int q0 = bqx * 128 + w * 32;
  const float c2 = 0.18033688f;     // 0.125 * log2(e)

  union { unsigned u[4]; bf16x8 v; } ones_u;
  ones_u.u[0] = 0x3F803F80u; ones_u.u[1] = 0x3F803F80u;
  ones_u.u[2] = 0x3F803F80u; ones_u.u[3] = 0x3F803F80u;
  const bf16x8 onesb = ones_u.v;

  bf16x8 qb[4];
#pragma unroll
  for (int ks = 0; ks < 4; ++ks) {
    union { bf16x8 v; __bf16 b[8]; } u;
    u.v = *(const bf16x8*)&q[base + (size_t)(q0 + l31) * 1024 + ks * 16 + h * 8];
#pragma unroll
    for (int j = 0; j < 8; ++j) u.b[j] = (__bf16)((float)u.b[j] * c2);
    qb[ks] = u.v;
  }

  f32x16 O[2] = {};
  f32x16 Osum = {};

  const int sm = tid >> 3, c0 = (tid & 7) * 8;
  const __bf16* gsrc = q + base + (size_t)(2 * sm) * 1024 + c0;

  __bf16* const K0 = &Kt[0][0];  __bf16* const V0 = &Vt[0][0];
  __bf16* const K1 = &Kt[1][0];  __bf16* const V1 = &Vt[1][0];

  bf16x8 v0 = *(const bf16x8*)&gsrc[0];
  bf16x8 v1 = *(const bf16x8*)&gsrc[1024];

  for (int t2 = 0; t2 < 16; ++t2) {
    ATTN_TILE(2 * t2,     K0, V0)
    ATTN_TILE(2 * t2 + 1, K1, V1)
  }

#pragma unroll
  for (int r = 0; r < 16; ++r) {
    const int qrow = (r & 3) + 8 * (r >> 2) + 4 * h;
    const float rs = 1.0f / Osum[r];
    o[base + (size_t)(q0 + qrow) * 1024 + l31]      = (__bf16)(O[0][r] * rs);
    o[base + (size_t)(q0 + qrow) * 1024 + 32 + l31] = (__bf16)(O[1][r] * rs);
  }
}

// ---------------- launch ----------------
extern "C" void kernel_launch(void* const* d_in, const int* in_sizes, int n_in,
                              void* d_out, int out_size, void* d_ws, size_t ws_size,
                              hipStream_t stream) {
  const float* x  = (const float*)d_in[0];
  const float* Wq = (const float*)d_in[1];
  const float* bq = (const float*)d_in[2];
  const float* Wo = (const float*)d_in[3];
  const float* bo = (const float*)d_in[4];

  char* ws = (char*)d_ws;
  __bf16* xb  = (__bf16*)(ws);                          // [0,8)   x bf16
  __bf16* ab  = (__bf16*)(ws);                          // [0,8)   attn out (aliases xb; xb dead)
  __bf16* wqb = (__bf16*)(ws + ((size_t)8  << 20));     // [8,10)
  __bf16* wob = (__bf16*)(ws + ((size_t)10 << 20));     // [10,12)
  __bf16* qb  = (__bf16*)(ws + ((size_t)12 << 20));     // [12,20) q projection

  const int M = 4096, N = 1024, K = 1024;

  k_cvt3<<<6144, 256, 0, stream>>>(x, Wq, Wo, xb, wqb, wob);

  k_gemm_bt<true ><<<dim3(8, 32), 256, 0, stream>>>(xb, wqb, bq, qb, M, N, K);
  k_attn          <<<dim3(16, 32), 256, 0, stream>>>(qb, ab);
  k_gemm_bt<false><<<dim3(8, 32), 256, 0, stream>>>(ab, wob, bo, d_out, M, N, K);
}

// Round 20
// 94.549 us; speedup vs baseline: 1.0908x; 1.0908x over previous
//
#include <hip/hip_runtime.h>
#include <hip/hip_bf16.h>

typedef __bf16 bf16x8 __attribute__((ext_vector_type(8)));
typedef float  f32x4  __attribute__((ext_vector_type(4)));
typedef float  f32x16 __attribute__((ext_vector_type(16)));

// async 16B global -> LDS (wave-uniform LDS base + lane*16)
__device__ __forceinline__ void gload_lds16(const void* g, void* l) {
  __builtin_amdgcn_global_load_lds(
      (const __attribute__((address_space(1))) unsigned int*)g,
      (__attribute__((address_space(3))) unsigned int*)l, 16, 0, 0);
}

// XCD-aware bijective remap for a (16, 32) grid: blocks sharing y land on ONE XCD.
__device__ __forceinline__ void xcd_remap(int& x, int& y) {
  const int lin = blockIdx.x + (blockIdx.y << 4);   // 0..511
  const int xcd = lin & 7, slot = lin >> 3;         // slot 0..63
  y = ((slot >> 4) << 3) + xcd;                     // 0..31
  x = slot & 15;                                    // 0..15
}

// ---------------- fused fp32 -> bf16 convert: x, Wq, Wo in one launch ----------------
__global__ void k_cvt3(const float* __restrict__ x, const float* __restrict__ wq,
                       const float* __restrict__ wo, __bf16* __restrict__ xb,
                       __bf16* __restrict__ wqb, __bf16* __restrict__ wob) {
  const int i = blockIdx.x * 256 + threadIdx.x;     // x 1M f4, wq 256K, wo 256K
  const float* s; __bf16* d; int j;
  if (i < 1048576)      { s = x;  d = xb;  j = i; }
  else if (i < 1310720) { s = wq; d = wqb; j = i - 1048576; }
  else                  { s = wo; d = wob; j = i - 1310720; }
  float4 v = ((const float4*)s)[j];
  union { __bf16 h[4]; uint2 u; } o;
  o.h[0] = (__bf16)v.x; o.h[1] = (__bf16)v.y;
  o.h[2] = (__bf16)v.z; o.h[3] = (__bf16)v.w;
  ((uint2*)d)[j] = o.u;
}

// ---------------- C[M,N] = A[M,K] @ B[N,K]^T + bias ----------------
// r16-proven: 128x64 tile, BK=32, 4 buffers, depth-2 prefetch, counted vmcnt(6),
// one raw barrier/iter, XCD remap (same-bm blocks share one XCD's L2 A-panel).
// grid (16,32) = 512 blocks = 2 blk/CU (8 waves/CU — the occupancy sweet spot;
// r19 proved 1 blk/CU loses more to latency than better LDS ratio gains).
template<bool OUT_BF16>
__global__ __launch_bounds__(256, 2)
void k_gemm_bt(const __bf16* __restrict__ A, const __bf16* __restrict__ B,
               const float* __restrict__ bias, void* __restrict__ C,
               int M, int N, int K) {
  __shared__ __align__(16) __bf16 At[4][128 * 32];   // 32KB
  __shared__ __align__(16) __bf16 Bt[4][64 * 32];    // 16KB
  const int tid  = threadIdx.x;
  const int lane = tid & 63;
  const int w    = tid >> 6;
  const int wr   = w >> 1, wc = w & 1;
  int bx, by; xcd_remap(bx, by);
  const int bm = by * 128, bn = bx * 64;

  f32x4 acc[4][2] = {};

  const __bf16* ga = A + (size_t)(bm + (tid >> 2)) * K + (tid & 3) * 8;
  const __bf16* gb = B + (size_t)(bn + (tid >> 2)) * K + (tid & 3) * 8;

#pragma unroll
  for (int p = 0; p < 2; ++p) {
    gload_lds16(ga + p * 32,                  &At[p][(w * 16) * 32]);
    gload_lds16(ga + p * 32 + (size_t)64 * K, &At[p][(64 + w * 16) * 32]);
    gload_lds16(gb + p * 32,                  &Bt[p][(w * 16) * 32]);
  }

  const int NIT = K / 32;                      // 32
  for (int it = 0; it < NIT; ++it) {
    const int cur = it & 3;
    if (it + 2 < NIT) {
      const int nb = (it + 2) & 3;
      const int k2 = (it + 2) * 32;
      gload_lds16(ga + k2,                  &At[nb][(w * 16) * 32]);
      gload_lds16(ga + k2 + (size_t)64 * K, &At[nb][(64 + w * 16) * 32]);
      gload_lds16(gb + k2,                  &Bt[nb][(w * 16) * 32]);
      asm volatile("s_waitcnt vmcnt(6)" ::: "memory");
    } else if (it + 2 == NIT) {
      asm volatile("s_waitcnt vmcnt(3)" ::: "memory");
    } else {
      asm volatile("s_waitcnt vmcnt(0)" ::: "memory");
    }
    __builtin_amdgcn_s_barrier();
    __builtin_amdgcn_sched_barrier(0);

    bf16x8 a[4], b[2];
#pragma unroll
    for (int mt = 0; mt < 4; ++mt)
      a[mt] = *(const bf16x8*)&At[cur][(wr * 64 + mt * 16 + (lane & 15)) * 32 + (lane >> 4) * 8];
#pragma unroll
    for (int nt = 0; nt < 2; ++nt)
      b[nt] = *(const bf16x8*)&Bt[cur][(wc * 32 + nt * 16 + (lane & 15)) * 32 + (lane >> 4) * 8];
    __builtin_amdgcn_s_setprio(1);
#pragma unroll
    for (int mt = 0; mt < 4; ++mt)
#pragma unroll
      for (int nt = 0; nt < 2; ++nt)
        acc[mt][nt] = __builtin_amdgcn_mfma_f32_16x16x32_bf16(a[mt], b[nt], acc[mt][nt], 0, 0, 0);
    __builtin_amdgcn_s_setprio(0);
  }

#pragma unroll
  for (int nt = 0; nt < 2; ++nt) {
    const int col = bn + wc * 32 + nt * 16 + (lane & 15);
    const float bv = bias[col];
#pragma unroll
    for (int mt = 0; mt < 4; ++mt) {
#pragma unroll
      for (int r = 0; r < 4; ++r) {
        const int row = bm + wr * 64 + mt * 16 + (lane >> 4) * 4 + r;
        const float v = acc[mt][nt][r] + bv;
        if (OUT_BF16) ((__bf16*)C)[(size_t)row * N + col] = (__bf16)v;
        else          ((float*)C)[(size_t)row * N + col]  = v;
      }
    }
  }
}

// ---------------- flash attention (Q = K = V), 32x32x16 MFMA ---------------- (r18 proven, verbatim)
#define SWZ2(row, col) ((row) * 64 + ((col) ^ (((((row) & 7) ^ ((row) >> 3)) & 7) << 3)))

#define ATTN_TILE(T, KB, VB)                                                  \
  {                                                                           \
    *(bf16x8*)&KB[SWZ2(2 * sm, c0)]     = v0;                                 \
    *(bf16x8*)&KB[SWZ2(2 * sm + 1, c0)] = v1;                                 \
    _Pragma("unroll")                                                         \
    for (int j = 0; j < 8; ++j) {                                             \
      union { __bf16 b[2]; unsigned u; } pk;                                  \
      pk.b[0] = v0[j]; pk.b[1] = v1[j];                                       \
      *(unsigned*)&VB[SWZ2(c0 + j, 2 * sm)] = pk.u;                           \
    }                                                                         \
    __syncthreads();                                                          \
    if ((T) < 31) {                                                           \
      v0 = *(const bf16x8*)&gsrc[(size_t)((T) + 1) * 64 * 1024];              \
      v1 = *(const bf16x8*)&gsrc[(size_t)((T) + 1) * 64 * 1024 + 1024];       \
    }                                                                         \
    f32x16 s[2] = {};                                                         \
    _Pragma("unroll")                                                         \
    for (int kvf = 0; kvf < 2; ++kvf) {                                       \
      __builtin_amdgcn_s_setprio(1);                                          \
      _Pragma("unroll")                                                       \
      for (int ks = 0; ks < 4; ++ks) {                                        \
        bf16x8 ka = *(const bf16x8*)&KB[SWZ2(kvf * 32 + l31, ks * 16 + h * 8)]; \
        s[kvf] = __builtin_amdgcn_mfma_f32_32x32x16_bf16(ka, qb[ks], s[kvf], 0, 0, 0); \
      }                                                                       \
      __builtin_amdgcn_s_setprio(0);                                          \
    }                                                                         \
    unsigned P[2][4][2];                                                      \
    _Pragma("unroll")                                                         \
    for (int kvf = 0; kvf < 2; ++kvf) {                                       \
      _Pragma("unroll")                                                       \
      for (int rq = 0; rq < 4; ++rq) {                                        \
        _Pragma("unroll")                                                     \
        for (int tt = 0; tt < 2; ++tt) {                                      \
          const float p0 = __builtin_amdgcn_exp2f(s[kvf][rq * 4 + tt * 2]);   \
          const float p1 = __builtin_amdgcn_exp2f(s[kvf][rq * 4 + tt * 2 + 1]); \
          union { __bf16 b[2]; unsigned u; } pk;                              \
          pk.b[0] = (__bf16)p0; pk.b[1] = (__bf16)p1;                         \
          P[kvf][rq][tt] = pk.u;                                              \
        }                                                                     \
      }                                                                       \
    }                                                                         \
    _Pragma("unroll")                                                         \
    for (int ko = 0; ko < 4; ++ko) {                                          \
      const int kvf = ko >> 1, rqa = (ko & 1) * 2, rqb = rqa + 1;             \
      asm volatile("v_permlane32_swap_b32 %0, %1"                             \
                   : "+v"(P[kvf][rqa][0]), "+v"(P[kvf][rqb][0]));             \
      asm volatile("v_permlane32_swap_b32 %0, %1"                             \
                   : "+v"(P[kvf][rqa][1]), "+v"(P[kvf][rqb][1]));             \
    }                                                                         \
    __builtin_amdgcn_s_setprio(1);                                            \
    _Pragma("unroll")                                                         \
    for (int ko = 0; ko < 4; ++ko) {                                          \
      const int kvf = ko >> 1, rqa = (ko & 1) * 2, rqb = rqa + 1;             \
      union { unsigned u[4]; bf16x8 v; } pu;                                  \
      pu.u[0] = P[kvf][rqa][0]; pu.u[1] = P[kvf][rqa][1];                     \
      pu.u[2] = P[kvf][rqb][0]; pu.u[3] = P[kvf][rqb][1];                     \
      Osum = __builtin_amdgcn_mfma_f32_32x32x16_bf16(pu.v, onesb, Osum, 0, 0, 0); \
      bf16x8 vb0 = *(const bf16x8*)&VB[SWZ2(l31,      ko * 16 + h * 8)];      \
      bf16x8 vb1 = *(const bf16x8*)&VB[SWZ2(32 + l31, ko * 16 + h * 8)];      \
      O[0] = __builtin_amdgcn_mfma_f32_32x32x16_bf16(pu.v, vb0, O[0], 0, 0, 0); \
      O[1] = __builtin_amdgcn_mfma_f32_32x32x16_bf16(pu.v, vb1, O[1], 0, 0, 0); \
    }                                                                         \
    __builtin_amdgcn_s_setprio(0);                                            \
  }

__global__ __launch_bounds__(256, 2)
void k_attn(const __bf16* __restrict__ q, __bf16* __restrict__ o) {
  __shared__ __align__(16) __bf16 Kt[2][64 * 64];
  __shared__ __align__(16) __bf16 Vt[2][64 * 64];
  const int tid = threadIdx.x, lane = tid & 63;
  const int w = tid >> 6;
  const int l31 = lane & 31, h = lane >> 5;
  int bqx, bh; xcd_remap(bqx, bh);
  const size_t base = ((size_t)(bh >> 4) * 2048) * 1024 + (bh & 15) * 64;
  const int q0 = bqx * 128 + w * 32;
  const float c2 = 0.18033688f;     // 0.125 * log2(e)

  union { unsigned u[4]; bf16x8 v; } ones_u;
  ones_u.u[0] = 0x3F803F80u; ones_u.u[1] = 0x3F803F80u;
  ones_u.u[2] = 0x3F803F80u; ones_u.u[3] = 0x3F803F80u;
  const bf16x8 onesb = ones_u.v;

  bf16x8 qb[4];
#pragma unroll
  for (int ks = 0; ks < 4; ++ks) {
    union { bf16x8 v; __bf16 b[8]; } u;
    u.v = *(const bf16x8*)&q[base + (size_t)(q0 + l31) * 1024 + ks * 16 + h * 8];
#pragma unroll
    for (int j = 0; j < 8; ++j) u.b[j] = (__bf16)((float)u.b[j] * c2);
    qb[ks] = u.v;
  }

  f32x16 O[2] = {};
  f32x16 Osum = {};

  const int sm = tid >> 3, c0 = (tid & 7) * 8;
  const __bf16* gsrc = q + base + (size_t)(2 * sm) * 1024 + c0;

  __bf16* const K0 = &Kt[0][0];  __bf16* const V0 = &Vt[0][0];
  __bf16* const K1 = &Kt[1][0];  __bf16* const V1 = &Vt[1][0];

  bf16x8 v0 = *(const bf16x8*)&gsrc[0];
  bf16x8 v1 = *(const bf16x8*)&gsrc[1024];

  for (int t2 = 0; t2 < 16; ++t2) {
    ATTN_TILE(2 * t2,     K0, V0)
    ATTN_TILE(2 * t2 + 1, K1, V1)
  }

#pragma unroll
  for (int r = 0; r < 16; ++r) {
    const int qrow = (r & 3) + 8 * (r >> 2) + 4 * h;
    const float rs = 1.0f / Osum[r];
    o[base + (size_t)(q0 + qrow) * 1024 + l31]      = (__bf16)(O[0][r] * rs);
    o[base + (size_t)(q0 + qrow) * 1024 + 32 + l31] = (__bf16)(O[1][r] * rs);
  }
}

// ---------------- launch ----------------
extern "C" void kernel_launch(void* const* d_in, const int* in_sizes, int n_in,
                              void* d_out, int out_size, void* d_ws, size_t ws_size,
                              hipStream_t stream) {
  const float* x  = (const float*)d_in[0];
  const float* Wq = (const float*)d_in[1];
  const float* bq = (const float*)d_in[2];
  const float* Wo = (const float*)d_in[3];
  const float* bo = (const float*)d_in[4];

  char* ws = (char*)d_ws;
  __bf16* xb  = (__bf16*)(ws);                          // [0,8)   x bf16
  __bf16* ab  = (__bf16*)(ws);                          // [0,8)   attn out (aliases xb; xb dead)
  __bf16* wqb = (__bf16*)(ws + ((size_t)8  << 20));     // [8,10)
  __bf16* wob = (__bf16*)(ws + ((size_t)10 << 20));     // [10,12)
  __bf16* qb  = (__bf16*)(ws + ((size_t)12 << 20));     // [12,20) q projection

  const int M = 4096, N = 1024, K = 1024;

  k_cvt3<<<6144, 256, 0, stream>>>(x, Wq, Wo, xb, wqb, wob);

  k_gemm_bt<true ><<<dim3(16, 32), 256, 0, stream>>>(xb, wqb, bq, qb, M, N, K);
  k_attn          <<<dim3(16, 32), 256, 0, stream>>>(qb, ab);
  k_gemm_bt<false><<<dim3(16, 32), 256, 0, stream>>>(ab, wob, bo, d_out, M, N, K);
}